// Round 6
// baseline (66.278 us; speedup 1.0000x reference)
//
#include <hip/hip_runtime.h>

// Problem constants (match reference)
#define BB 2048   // batch
#define DD 512    // dim
#define RR 32     // relations

// Tiling: block = (relation r, e-chunk nc of NB, d-chunk kc of KB)
#define NB 64                // e-range per block
#define KB 128               // d-range per block
#define KS 32                // d per K-step (MFMA K)
#define NKS (KB / KS)        // 4 K-steps, all staged up-front
#define MT 80                // sample tile
#define SLCAP 256            // sample-list capacity (n_r ~64, 6-sigma < 120)
#define NPART 32             // nc(8) x kc(4) partial planes per relation

#define A_STRIDE 132         // bf16; ~2-way max on b128 reads (free)
#define W_STRIDE 34          // bf16; ~2-way max (free)

typedef __attribute__((ext_vector_type(8))) short bf16x8;
typedef __attribute__((ext_vector_type(4))) float f32x4;

__device__ __forceinline__ unsigned short f2bf(float f) {
    unsigned u = __float_as_uint(f);
    return (unsigned short)((u + 0x7FFFu + ((u >> 16) & 1u)) >> 16);  // RNE
}
__device__ __forceinline__ unsigned pack2(float a, float b) {
    return (unsigned)f2bf(a) | ((unsigned)f2bf(b) << 16);
}

__launch_bounds__(256, 4)
__global__ void k_main(const float* __restrict__ head,
                       const float* __restrict__ tail,
                       const int* __restrict__ rel,
                       const float* __restrict__ W,
                       const float* __restrict__ b,
                       float* __restrict__ part,
                       int* __restrict__ cnt,
                       float* __restrict__ out) {
    // XCD-swizzled decode: all 32 blocks of a relation land on one XCD.
    const int bid = blockIdx.x;
    const int x = bid & 7, p = bid >> 3;
    const int r  = (x << 2) | (p >> 5);
    const int nc = (p >> 2) & 7;
    const int kc = p & 3;
    const int e0 = nc * NB;
    const int k0 = kc * KB;
    const int jplane = (nc << 2) | kc;
    const int tid = threadIdx.x;
    const int wave = tid >> 6;
    const int lane = tid & 63;
    const int l15 = lane & 15, lg = lane >> 4;

    __shared__ unsigned short A_lds[MT * A_STRIDE];        // 21.1 KiB
    __shared__ unsigned short W_lds[NKS][NB * W_STRIDE];   // 17.4 KiB
    __shared__ int slist[SLCAP];
    __shared__ float scpart[MT];
    __shared__ int cntS;
    __shared__ float bsS;
    __shared__ int lastS;

    if (tid == 0) cntS = 0;

    // ---- issue the block's ENTIRE W chunk (64e x 128d fp32) immediately
    const float* Wbase = W + ((size_t)r * DD + e0) * DD + k0;
    float4 wreg[8];
    #pragma unroll
    for (int i = 0; i < 8; i++) {
        int idx = i * 256 + tid;
        int row = idx >> 5, fc = idx & 31;                 // 32 float4 per row
        wreg[i] = *(const float4*)(Wbase + (size_t)row * DD + fc * 4);
    }

    __syncthreads();   // cntS = 0 visible

    // ---- build this relation's sample list (rel[] is 8KB, L2/L3-resident)
    {
        const int4* rp = (const int4*)rel;
        #pragma unroll
        for (int j = 0; j < 2; j++) {
            int4 v = rp[tid * 2 + j];
            int base = (tid * 2 + j) * 4;
            if (v.x == r) { int q = atomicAdd(&cntS, 1); if (q < SLCAP) slist[q] = base; }
            if (v.y == r) { int q = atomicAdd(&cntS, 1); if (q < SLCAP) slist[q] = base + 1; }
            if (v.z == r) { int q = atomicAdd(&cntS, 1); if (q < SLCAP) slist[q] = base + 2; }
            if (v.w == r) { int q = atomicAdd(&cntS, 1); if (q < SLCAP) slist[q] = base + 3; }
        }
    }
    // ---- bias partial for this e-range (folded in by kc==0 blocks only)
    if (wave == 0) {
        float v = b[r * DD + e0 + lane];
        #pragma unroll
        for (int off = 32; off; off >>= 1) v += __shfl_xor(v, off);
        if (lane == 0) bsS = v;
    }
    __syncthreads();   // slist/cntS/bsS ready

    const int n = min(cntS, SLCAP);
    const float biasv = (kc == 0) ? bsS : 0.f;
    const int tn0 = min(MT, n);

    // ---- issue tile-0 tail loads NOW (they return during the W vmcnt drain)
    float4 treg[10];
    #pragma unroll
    for (int i = 0; i < 10; i++) {                         // MT*KB/4/256 = 10
        int idx = i * 256 + tid;
        int row = idx >> 5, fc = idx & 31;
        treg[i] = make_float4(0.f, 0.f, 0.f, 0.f);
        if (row < tn0)
            treg[i] = *(const float4*)(tail + (size_t)slist[row] * DD + k0 + fc * 4);
    }

    // ---- stage W regs -> 4 K-step LDS buffers (waits vmcnt for W only)
    #pragma unroll
    for (int i = 0; i < 8; i++) {
        int idx = i * 256 + tid;
        int row = idx >> 5, fc = idx & 31;
        int ks = fc >> 3, c8 = fc & 7;
        unsigned* pw = (unsigned*)&W_lds[ks][row * W_STRIDE + c8 * 4];
        pw[0] = pack2(wreg[i].x, wreg[i].y);
        pw[1] = pack2(wreg[i].z, wreg[i].w);
    }

    for (int ts = 0; ts < n; ts += MT) {
        const int tn = min(MT, n - ts);
        if (tid < MT) scpart[tid] = biasv;

        if (ts == 0) {
            // tile 0: pack preloaded regs
            #pragma unroll
            for (int i = 0; i < 10; i++) {
                int idx = i * 256 + tid;
                int row = idx >> 5, fc = idx & 31;
                unsigned* pa = (unsigned*)&A_lds[row * A_STRIDE + fc * 4];
                pa[0] = pack2(treg[i].x, treg[i].y);
                pa[1] = pack2(treg[i].z, treg[i].w);
            }
        } else {
            // rare overflow tiles: load + pack inline
            #pragma unroll
            for (int i = 0; i < 10; i++) {
                int idx = i * 256 + tid;
                int row = idx >> 5, fc = idx & 31;
                float4 v = make_float4(0.f, 0.f, 0.f, 0.f);
                if (row < tn)
                    v = *(const float4*)(tail + (size_t)slist[ts + row] * DD + k0 + fc * 4);
                unsigned* pa = (unsigned*)&A_lds[row * A_STRIDE + fc * 4];
                pa[0] = pack2(v.x, v.y);
                pa[1] = pack2(v.z, v.w);
            }
        }
        __syncthreads();   // A_lds (and on iter 0, W_lds) visible

        f32x4 acc[MT / 16];
        #pragma unroll
        for (int m = 0; m < MT / 16; m++) acc[m] = (f32x4){0.f, 0.f, 0.f, 0.f};

        #pragma unroll
        for (int ks = 0; ks < NKS; ks++) {
            bf16x8 bfr = *(const bf16x8*)&W_lds[ks][(wave * 16 + l15) * W_STRIDE + lg * 8];
            #pragma unroll
            for (int m = 0; m < MT / 16; m++) {
                bf16x8 af = *(const bf16x8*)&A_lds[(m * 16 + l15) * A_STRIDE + ks * KS + lg * 8];
                acc[m] = __builtin_amdgcn_mfma_f32_16x16x32_bf16(af, bfr, acc[m], 0, 0, 0);
            }
        }

        // ---- epilogue: scpart[s] += sum_e acc[s,e] * head[s,e]
        // C layout: col(e) = l15, row(s) = 4*lg + q  (m89-verified)
        const int ebase = e0 + wave * 16;
        #pragma unroll
        for (int m = 0; m < MT / 16; m++) {
            float v[4];
            #pragma unroll
            for (int q = 0; q < 4; q++) {
                int sl = m * 16 + lg * 4 + q;
                int si = min(sl, tn - 1);
                float h = head[(size_t)slist[ts + si] * DD + ebase + l15];
                v[q] = acc[m][q] * h;                      // pad rows: acc==0
            }
            #pragma unroll
            for (int q = 0; q < 4; q++) {
                #pragma unroll
                for (int off = 1; off < 16; off <<= 1)
                    v[q] += __shfl_xor(v[q], off);         // reduce over e (l15)
                if (l15 == 0) {
                    int sl = m * 16 + lg * 4 + q;
                    if (sl < tn) atomicAdd(&scpart[sl], v[q]);
                }
            }
        }
        __syncthreads();
        // plane (nc,kc) of each sample written by exactly this block: plain store
        if (tid < tn) part[(size_t)jplane * BB + slist[ts + tid]] = scpart[tid];
        __syncthreads();   // protect scpart/A_lds before next tile
    }

    // ---- last-arriving block of this relation reduces the 32 planes
    // (plane stores drained to L2 by the loop's trailing __syncthreads)
    if (tid == 0) {
        __threadfence();                       // device-scope release
        int old = atomicAdd(&cnt[r], 1);       // device-scope by default
        lastS = (old == NPART - 1);
    }
    __syncthreads();
    if (lastS) {
        __threadfence();                       // device-scope acquire
        for (int s = tid; s < n; s += 256) {
            int gi = slist[s];
            float acc = 0.f;
            #pragma unroll
            for (int j = 0; j < NPART; j++) acc += part[(size_t)j * BB + gi];
            out[gi] = acc;                     // fixed order -> deterministic
        }
    }
}

extern "C" void kernel_launch(void* const* d_in, const int* in_sizes, int n_in,
                              void* d_out, int out_size, void* d_ws, size_t ws_size,
                              hipStream_t stream) {
    const float* head = (const float*)d_in[0];
    const float* tail = (const float*)d_in[1];
    const int*   rel  = (const int*)d_in[2];
    const float* W    = (const float*)d_in[3];
    const float* b    = (const float*)d_in[4];
    float* out  = (float*)d_out;
    float* part = (float*)d_ws;                              // 32 x 2048 floats
    int*   cnt  = (int*)((char*)d_ws + (size_t)NPART * BB * sizeof(float));

    hipMemsetAsync(cnt, 0, RR * sizeof(int), stream);        // graph-safe
    k_main<<<RR * (DD / NB) * (DD / KB), 256, 0, stream>>>(head, tail, rel, W, b,
                                                           part, cnt, out);
}

// Round 7
// 28.102 us; speedup vs baseline: 2.3585x; 2.3585x over previous
//
#include <hip/hip_runtime.h>

// Problem constants (match reference)
#define BB 2048   // batch
#define DD 512    // dim
#define RR 32     // relations

// Tiling: block = (relation r, e-chunk nc of NB, d-chunk kc of KB)
#define NB 64                // e-range per block
#define KB 128               // d-range per block
#define KS 32                // d per K-step (MFMA K)
#define NKS (KB / KS)        // 4 K-steps, B-fragments held in registers
#define MT 80                // sample tile
#define SLCAP 256            // sample-list capacity (n_r ~64, 6-sigma < 120)
#define NPART 32             // nc(8) x kc(4) partial planes per relation

#define A_STRIDE 132         // bf16 row stride for tail tile
#define HS 68                // bf16 row stride for head tile (lg groups 8 banks apart)

typedef __attribute__((ext_vector_type(8))) short bf16x8;
typedef __attribute__((ext_vector_type(4))) float f32x4;

__device__ __forceinline__ unsigned short f2bf(float f) {
    unsigned u = __float_as_uint(f);
    return (unsigned short)((u + 0x7FFFu + ((u >> 16) & 1u)) >> 16);  // RNE
}
__device__ __forceinline__ unsigned pack2(float a, float b) {
    return (unsigned)f2bf(a) | ((unsigned)f2bf(b) << 16);
}
__device__ __forceinline__ float bf2f(unsigned short u) {
    return __uint_as_float((unsigned)u << 16);
}

__launch_bounds__(256, 4)
__global__ void k_main(const float* __restrict__ head,
                       const float* __restrict__ tail,
                       const int* __restrict__ rel,
                       const float* __restrict__ W,
                       const float* __restrict__ b,
                       float* __restrict__ part) {
    // XCD-swizzled decode: all 32 blocks of a relation land on one XCD.
    const int bid = blockIdx.x;
    const int x = bid & 7, p = bid >> 3;
    const int r  = (x << 2) | (p >> 5);
    const int nc = (p >> 2) & 7;
    const int kc = p & 3;
    const int e0 = nc * NB;
    const int k0 = kc * KB;
    const int jplane = (nc << 2) | kc;
    const int tid = threadIdx.x;
    const int wave = tid >> 6;
    const int lane = tid & 63;
    const int l15 = lane & 15, lg = lane >> 4;

    __shared__ unsigned short A_lds[MT * A_STRIDE];        // 21.1 KiB
    __shared__ unsigned short H_lds[MT * HS];              // 10.9 KiB
    __shared__ int slist[SLCAP];
    __shared__ float scpart[MT];
    __shared__ int cntS;
    __shared__ float bsS;

    if (tid == 0) cntS = 0;
    __syncthreads();           // nothing in flight yet: cheap drain

    // ---- issue rel + bias loads FIRST (small, L2-hot; vmcnt decrements in
    //      issue order, so consuming them does not wait on W)
    const int4* rp = (const int4*)rel;
    int4 rv0 = rp[tid * 2 + 0];
    int4 rv1 = rp[tid * 2 + 1];
    float bv = (wave == 0) ? b[r * DD + e0 + lane] : 0.f;

    // ---- issue this thread's OWN W B-fragment: rows e=wave*16+l15,
    //      cols ks*32+lg*8 (+4). Every W element read by exactly one thread.
    const float* Wrow = W + ((size_t)r * DD + e0 + wave * 16 + l15) * DD + k0 + lg * 8;
    float4 wv[NKS][2];
    #pragma unroll
    for (int ks = 0; ks < NKS; ks++) {
        wv[ks][0] = *(const float4*)(Wrow + ks * KS);
        wv[ks][1] = *(const float4*)(Wrow + ks * KS + 4);
    }

    // ---- scan rel -> slist (LDS atomics); consumes only rv0/rv1
    {
        int base = tid * 8;
        if (rv0.x == r) { int q = atomicAdd(&cntS, 1); if (q < SLCAP) slist[q] = base; }
        if (rv0.y == r) { int q = atomicAdd(&cntS, 1); if (q < SLCAP) slist[q] = base + 1; }
        if (rv0.z == r) { int q = atomicAdd(&cntS, 1); if (q < SLCAP) slist[q] = base + 2; }
        if (rv0.w == r) { int q = atomicAdd(&cntS, 1); if (q < SLCAP) slist[q] = base + 3; }
        if (rv1.x == r) { int q = atomicAdd(&cntS, 1); if (q < SLCAP) slist[q] = base + 4; }
        if (rv1.y == r) { int q = atomicAdd(&cntS, 1); if (q < SLCAP) slist[q] = base + 5; }
        if (rv1.z == r) { int q = atomicAdd(&cntS, 1); if (q < SLCAP) slist[q] = base + 6; }
        if (rv1.w == r) { int q = atomicAdd(&cntS, 1); if (q < SLCAP) slist[q] = base + 7; }
    }
    // ---- bias partial for this e-range (folded in by kc==0 blocks only)
    {
        float v = bv;
        #pragma unroll
        for (int off = 32; off; off >>= 1) v += __shfl_xor(v, off);
        if (wave == 0 && lane == 0) bsS = v;
    }

    // RAW barrier (no vmcnt drain -> W loads stay in flight across it)
    asm volatile("s_waitcnt lgkmcnt(0)" ::: "memory");
    __builtin_amdgcn_s_barrier();
    __builtin_amdgcn_sched_barrier(0);

    const int n = min(cntS, SLCAP);
    const float biasv = (kc == 0) ? bsS : 0.f;

    bf16x8 bfr[NKS];
    bool converted = false;

    for (int ts = 0; ts < n; ts += MT) {
        const int tn = min(MT, n - ts);
        if (ts > 0) __syncthreads();           // protect scpart/A_lds/H_lds reuse
        if (tid < MT) scpart[tid] = biasv;

        // ---- stage tail[tn x KB] fp32 -> bf16 A_lds; pad rows zeroed
        #pragma unroll
        for (int i = 0; i < (MT * KB / 4) / 256; i++) {    // 10 iters
            int idx = i * 256 + tid;
            int row = idx >> 5, fc = idx & 31;
            float4 v = make_float4(0.f, 0.f, 0.f, 0.f);
            if (row < tn)
                v = *(const float4*)(tail + (size_t)slist[ts + row] * DD + k0 + fc * 4);
            unsigned* pa = (unsigned*)&A_lds[row * A_STRIDE + fc * 4];
            pa[0] = pack2(v.x, v.y);
            pa[1] = pack2(v.z, v.w);
        }
        // ---- stage head[tn x NB] fp32 -> bf16 H_lds (epilogue reads LDS)
        #pragma unroll
        for (int i = 0; i < (MT * NB / 4) / 256; i++) {    // 5 iters
            int idx = i * 256 + tid;
            int row = idx >> 4, fc = idx & 15;
            float4 v = make_float4(0.f, 0.f, 0.f, 0.f);
            if (row < tn)
                v = *(const float4*)(head + (size_t)slist[ts + row] * DD + e0 + fc * 4);
            unsigned* ph = (unsigned*)&H_lds[row * HS + fc * 4];
            ph[0] = pack2(v.x, v.y);
            ph[1] = pack2(v.z, v.w);
        }
        __syncthreads();   // full drain: staging visible; W regs ready to use

        // ---- convert W fragment to bf16 once (vmcnt already drained)
        if (!converted) {
            #pragma unroll
            for (int ks = 0; ks < NKS; ks++) {
                union { unsigned u[4]; bf16x8 v; } bb;
                bb.u[0] = pack2(wv[ks][0].x, wv[ks][0].y);
                bb.u[1] = pack2(wv[ks][0].z, wv[ks][0].w);
                bb.u[2] = pack2(wv[ks][1].x, wv[ks][1].y);
                bb.u[3] = pack2(wv[ks][1].z, wv[ks][1].w);
                bfr[ks] = bb.v;
            }
            converted = true;
        }

        f32x4 acc[MT / 16];
        #pragma unroll
        for (int m = 0; m < MT / 16; m++) acc[m] = (f32x4){0.f, 0.f, 0.f, 0.f};

        #pragma unroll
        for (int ks = 0; ks < NKS; ks++) {
            #pragma unroll
            for (int m = 0; m < MT / 16; m++) {
                bf16x8 af = *(const bf16x8*)&A_lds[(m * 16 + l15) * A_STRIDE + ks * KS + lg * 8];
                acc[m] = __builtin_amdgcn_mfma_f32_16x16x32_bf16(af, bfr[ks], acc[m], 0, 0, 0);
            }
        }

        // ---- epilogue: scpart[s] += sum_e acc[s,e] * head[s,e]
        // C layout: col(e) = l15, row(s) = 4*lg + q  (m89-verified)
        #pragma unroll
        for (int m = 0; m < MT / 16; m++) {
            float v[4];
            #pragma unroll
            for (int q = 0; q < 4; q++) {
                int sl = m * 16 + lg * 4 + q;
                int si = min(sl, tn - 1);
                float h = bf2f(H_lds[si * HS + wave * 16 + l15]);
                v[q] = acc[m][q] * h;                      // pad rows: acc==0
            }
            #pragma unroll
            for (int q = 0; q < 4; q++) {
                #pragma unroll
                for (int off = 1; off < 16; off <<= 1)
                    v[q] += __shfl_xor(v[q], off);         // reduce over e (l15)
                if (l15 == 0) {
                    int sl = m * 16 + lg * 4 + q;
                    if (sl < tn) atomicAdd(&scpart[sl], v[q]);
                }
            }
        }
        __syncthreads();
        // plane (nc,kc) of each sample written by exactly this block: plain store
        if (tid < tn) part[(size_t)jplane * BB + slist[ts + tid]] = scpart[tid];
    }
}

__global__ void k_reduce(const float* __restrict__ part, float* __restrict__ out) {
    int i = blockIdx.x * 256 + threadIdx.x;
    float s = 0.f;
    #pragma unroll
    for (int j = 0; j < NPART; j++) s += part[(size_t)j * BB + i];
    out[i] = s;
}

extern "C" void kernel_launch(void* const* d_in, const int* in_sizes, int n_in,
                              void* d_out, int out_size, void* d_ws, size_t ws_size,
                              hipStream_t stream) {
    const float* head = (const float*)d_in[0];
    const float* tail = (const float*)d_in[1];
    const int*   rel  = (const int*)d_in[2];
    const float* W    = (const float*)d_in[3];
    const float* b    = (const float*)d_in[4];
    float* out  = (float*)d_out;
    float* part = (float*)d_ws;   // NPART x BB floats = 256 KiB

    k_main<<<RR * (DD / NB) * (DD / KB), 256, 0, stream>>>(head, tail, rel, W, b, part);
    k_reduce<<<BB / 256, 256, 0, stream>>>(part, out);
}